// Round 1
// baseline (163.101 us; speedup 1.0000x reference)
//
#include <hip/hip_runtime.h>
#include <hip/hip_bf16.h>
#include <math.h>

#define Bb 4
#define Ss 2048
#define Ee 512
#define Hh 8
#define Dd 64
#define HD 512
#define Mm (Bb*Ss)
#define RPB 1536      // compacted rows-per-batch capacity (cnt ~1024)
#define QT2 12        // 128-row q-tiles per batch (RPB/128)
#define AT 24

using bf16x8 = __attribute__((ext_vector_type(8))) short;
using f32x4  = __attribute__((ext_vector_type(4))) float;
using f32x16 = __attribute__((ext_vector_type(16))) float;

typedef __attribute__((address_space(1))) const unsigned int gu32;
typedef __attribute__((address_space(3))) unsigned int lu32;
__device__ inline void glds16(const void* g, void* l) {
    __builtin_amdgcn_global_load_lds((gu32*)g, (lu32*)l, 16, 0, 0);
}

__device__ inline unsigned short f2bf(float f) {
    unsigned int u = __float_as_uint(f);
    unsigned int r = (u + 0x7fffu + ((u >> 16) & 1u)) >> 16;
    return (unsigned short)r;
}
__device__ inline float bf2f(unsigned short u) {
    return __uint_as_float((unsigned int)u << 16);
}
__device__ inline unsigned int cvtpk(float a, float b) {
    float2 t; t.x = a; t.y = b;
    union { __hip_bfloat162 h; unsigned int u; } z;
    z.h = __float22bfloat162_rn(t);
    return z.u;
}

// ---------------------------------------------------------------------------
// Kernel 1: prep2 = wconv (256 blocks) + scan+gather+xpart (64 blocks).
// ---------------------------------------------------------------------------
__global__ __launch_bounds__(256) void prep2(
    const float* __restrict__ x, const int* __restrict__ pad,
    const float* __restrict__ Wq, const float* __restrict__ Wk,
    const float* __restrict__ Wv, const float* __restrict__ Wo,
    unsigned short* __restrict__ Wt, unsigned short* __restrict__ xc,
    float* __restrict__ xpart, int* __restrict__ idx, int* __restrict__ cnt)
{
    __shared__ union ShMem {
        float T[64][68];
        struct { int sc[256]; int rk[128]; float sm[4][512]; } g;
    } sh;
    const int bi = blockIdx.x, tid = threadIdx.x;

    if (bi < 256) {
        const int w = bi >> 6;
        const float* W = (w == 0) ? Wq : (w == 1) ? Wk : (w == 2) ? Wv : Wo;
        const int tk0 = ((bi >> 3) & 7) * 64, tn0 = (bi & 7) * 64;
        #pragma unroll
        for (int l = 0; l < 4; ++l) {
            int fi = tid + l * 256;
            int r = fi >> 4, c4 = (fi & 15) * 4;
            *(float4*)&sh.T[r][c4] = *(const float4*)(W + (size_t)(tk0 + r) * Ee + tn0 + c4);
        }
        __syncthreads();
        #pragma unroll
        for (int l = 0; l < 4; ++l) {
            int fi = tid + l * 256;
            int r2 = fi >> 4, c4 = (fi & 15) * 4;
            uint2 o;
            o.x = cvtpk(sh.T[c4 + 0][r2], sh.T[c4 + 1][r2]);
            o.y = cvtpk(sh.T[c4 + 2][r2], sh.T[c4 + 3][r2]);
            *(uint2*)(Wt + (size_t)w * 262144 + (size_t)(tn0 + r2) * Ee + tk0 + c4) = o;
        }
        return;
    }

    // ---- gather blocks: gb = (b, chunk i of 128 rows) ----
    const int gb = bi - 256;
    const int b = gb >> 4, i = gb & 15;

    int loc[8], c = 0;
    #pragma unroll
    for (int j = 0; j < 8; ++j) {
        loc[j] = pad[b * Ss + tid * 8 + j];
        c += (loc[j] == 0);
    }
    sh.g.sc[tid] = c;
    __syncthreads();
    for (int s = 1; s < 256; s <<= 1) {
        int v = (tid >= s) ? sh.g.sc[tid - s] : 0;
        __syncthreads();
        sh.g.sc[tid] += v;
        __syncthreads();
    }
    if (tid >= i * 16 && tid < i * 16 + 16) {
        int off = sh.g.sc[tid] - c;
        int lbase = (tid - i * 16) * 8;
        #pragma unroll
        for (int j = 0; j < 8; ++j) {
            if (loc[j] == 0) {
                idx[b * Ss + off] = tid * 8 + j;
                sh.g.rk[lbase + j] = off;
                ++off;
            } else sh.g.rk[lbase + j] = -1;
        }
    }
    if (i == 15 && tid == 255) cnt[b] = sh.g.sc[255];
    __syncthreads();

    const int c8 = (tid & 63) * 8, grp = tid >> 6;
    float a8[8] = {};
    for (int it = 0; it < 32; ++it) {
        int lr = grp * 32 + it;
        int s = i * 128 + lr;
        const float* pr = x + ((size_t)b * Ss + s) * Ee + c8;
        float4 f0 = *(const float4*)pr;
        float4 f1 = *(const float4*)(pr + 4);
        a8[0] += f0.x; a8[1] += f0.y; a8[2] += f0.z; a8[3] += f0.w;
        a8[4] += f1.x; a8[5] += f1.y; a8[6] += f1.z; a8[7] += f1.w;
        int rkk = sh.g.rk[lr];
        if (rkk >= 0) {
            uint4 v;
            v.x = cvtpk(f0.x, f0.y); v.y = cvtpk(f0.z, f0.w);
            v.z = cvtpk(f1.x, f1.y); v.w = cvtpk(f1.z, f1.w);
            *(uint4*)(xc + ((size_t)b * RPB + rkk) * Ee + c8) = v;
        }
    }
    #pragma unroll
    for (int j = 0; j < 8; ++j) sh.g.sm[grp][c8 + j] = a8[j];
    __syncthreads();
    int c0 = tid * 2;
    float s0 = sh.g.sm[0][c0] + sh.g.sm[1][c0] + sh.g.sm[2][c0] + sh.g.sm[3][c0];
    float s1 = sh.g.sm[0][c0 + 1] + sh.g.sm[1][c0 + 1] + sh.g.sm[2][c0 + 1] + sh.g.sm[3][c0 + 1];
    float2 o; o.x = s0; o.y = s1;
    *(float2*)(xpart + (size_t)(b * 16 + i) * Ee + c0) = o;
}

// ---------------------------------------------------------------------------
// Kernel 2: gemm_qkvt, 64x64 tiles, XOR-swizzled LDS.  Grid (4b*192, 1, 3).
// ---------------------------------------------------------------------------
__global__ __launch_bounds__(256) void gemm_qkvt(
    const unsigned short* __restrict__ xc, const unsigned short* __restrict__ Wt,
    const float* __restrict__ bq, const float* __restrict__ bk, const float* __restrict__ bv,
    const int* __restrict__ cnt, const float* __restrict__ xpart,
    unsigned short* __restrict__ qo, unsigned short* __restrict__ ko,
    unsigned short* __restrict__ vt, float* __restrict__ vmw)
{
    const int z = blockIdx.z;
    const int bx = blockIdx.x;
    const int b = bx / 192, t = bx - b * 192;
    const int at = (z < 2) ? (t >> 3) : (t & 7);
    const int bt = (z < 2) ? (t & 7) : (t >> 3);
    const int cntb = cnt[b];
    const int tid = threadIdx.x, lane = tid & 63, wv = tid >> 6;
    const int quad = lane >> 4, l15 = lane & 15;
    const int wm = (wv >> 1) * 32, wn = (wv & 1) * 32;
    const int sw = (l15 >> 1) & 3;

    __shared__ unsigned short As0[64][32], Bs0[64][32];
    __shared__ unsigned short As1[64][32], Bs1[64][32];

    if (z == 2 && bt == AT - 1) {
        __shared__ float xm[512];
        for (int kk = tid; kk < 512; kk += 256) {
            float s = 0.f;
            #pragma unroll
            for (int p = 0; p < 16; ++p) s += xpart[(size_t)(b * 16 + p) * Ee + kk];
            xm[kk] = s;
        }
        __syncthreads();
        int col = at * 64 + (tid >> 2);
        int kh = (tid & 3) * 128;
        const unsigned short* wrow = Wt + (size_t)2 * 262144 + (size_t)col * Ee + kh;
        float s = 0.f;
        #pragma unroll 8
        for (int kk = 0; kk < 128; ++kk) s += xm[kh + kk] * bf2f(wrow[kk]);
        s += __shfl_xor(s, 1);
        s += __shfl_xor(s, 2);
        if ((tid & 3) == 0) vmw[(size_t)b * HD + col] = s * (1.0f / 2048.0f) + bv[col];
        return;
    }

    const int xcTile = (z < 2) ? at : bt;
    if (xcTile * 64 >= cntb) return;

    const unsigned short *Ap, *Bp;
    if (z < 2) {
        Ap = xc + ((size_t)b * RPB + at * 64) * Ee;
        Bp = Wt + (size_t)z * 262144 + (size_t)bt * 64 * Ee;
    } else {
        Ap = Wt + (size_t)2 * 262144 + (size_t)at * 64 * Ee;
        Bp = xc + ((size_t)b * RPB + bt * 64) * Ee;
    }

    f32x4 acc[2][2] = {};

    auto stage = [&](unsigned short (&A)[64][32], unsigned short (&B)[64][32], int k0) {
        int r = tid >> 2, c = tid & 3;
        int cg = (c ^ ((r >> 1) & 3)) * 8;
        glds16(Ap + (size_t)r * Ee + k0 + cg, &A[r][c * 8]);
        glds16(Bp + (size_t)r * Ee + k0 + cg, &B[r][c * 8]);
    };
    auto compute = [&](const unsigned short (&A)[64][32], const unsigned short (&B)[64][32]) {
        bf16x8 af[2], bfr[2];
        #pragma unroll
        for (int ms = 0; ms < 2; ++ms) af[ms] = *(const bf16x8*)&A[wm + ms * 16 + l15][(quad ^ sw) * 8];
        #pragma unroll
        for (int ns = 0; ns < 2; ++ns) bfr[ns] = *(const bf16x8*)&B[wn + ns * 16 + l15][(quad ^ sw) * 8];
        #pragma unroll
        for (int ms = 0; ms < 2; ++ms)
            #pragma unroll
            for (int ns = 0; ns < 2; ++ns)
                acc[ms][ns] = __builtin_amdgcn_mfma_f32_16x16x32_bf16(af[ms], bfr[ns], acc[ms][ns], 0, 0, 0);
    };

    stage(As0, Bs0, 0);
    for (int ki = 0; ki < 16; ki += 2) {
        __syncthreads();
        if (ki + 1 < 16) stage(As1, Bs1, (ki + 1) * 32);
        compute(As0, Bs0);
        __syncthreads();
        if (ki + 2 < 16) stage(As0, Bs0, (ki + 2) * 32);
        compute(As1, Bs1);
    }

    if (z < 2) {
        const float* bias = z ? bk : bq;
        unsigned short* dst = z ? ko : qo;
        #pragma unroll
        for (int ns = 0; ns < 2; ++ns) {
            int col = bt * 64 + wn + ns * 16 + l15;
            float bb = bias[col];
            #pragma unroll
            for (int ms = 0; ms < 2; ++ms) {
                #pragma unroll
                for (int r = 0; r < 4; ++r) {
                    int m = at * 64 + wm + ms * 16 + quad * 4 + r;
                    float val = acc[ms][ns][r] + bb;
                    if (z == 0) val *= 0.18033688f;   // 0.125 * log2(e)
                    dst[((size_t)b * RPB + m) * HD + col] = f2bf(val);
                }
            }
        }
    } else {
        #pragma unroll
        for (int ms = 0; ms < 2; ++ms) {
            #pragma unroll
            for (int r = 0; r < 4; ++r) {
                int dg = at * 64 + wm + ms * 16 + quad * 4 + r;
                float bb = bv[dg];
                #pragma unroll
                for (int ns = 0; ns < 2; ++ns) {
                    int col = bt * 64 + wn + ns * 16 + l15;
                    vt[((size_t)b * HD + dg) * RPB + col] = f2bf(acc[ms][ns][r] + bb);
                }
            }
        }
    }
}

// ---------------------------------------------------------------------------
// Kernel 3: attention, QBLK=128 (4 waves x 32q), 32x32x16 MFMA, swapped QK^T,
// in-register P via cvt_pk + v_permlane32_swap, double-buffered K/V staging
// with counted vmcnt.  Grid (32 bh, QT2+1, 2).  k-split=2.
// y==QT2 (half0, bh<8): out_pad = concat_h(vmean)@Wo + bo.
// ---------------------------------------------------------------------------
__global__ __launch_bounds__(256, 2) void attn(
    const unsigned short* __restrict__ qc, const unsigned short* __restrict__ kc,
    const unsigned short* __restrict__ vtc, const int* __restrict__ cnt,
    unsigned short* __restrict__ pO, float* __restrict__ pL,
    const float* __restrict__ vmw, const unsigned short* __restrict__ Wt,
    const float* __restrict__ bo, float* __restrict__ opad)
{
    __shared__ unsigned short Ks[2][64][64], Vs[2][64][64];

    const int tid = threadIdx.x, wv = tid >> 6, lane = tid & 63;
    const int l31 = lane & 31, hlf = lane >> 5;
    const int bh = blockIdx.x, b = bh >> 3, hd = bh & 7;
    const int qt = blockIdx.y, half = blockIdx.z;

    if (qt >= QT2) {
        if (half || bh >= 8) return;
        const int b2 = bh >> 1, seg = bh & 1;
        float* vm = (float*)&Ks[0][0][0];
        for (int t = tid; t < 512; t += 256) vm[t] = vmw[(size_t)b2 * HD + t];
        __syncthreads();
        int ccc = seg * 256 + tid;
        const unsigned short* wrow = Wt + (size_t)3 * 262144 + (size_t)ccc * HD;
        float s = 0.f;
        #pragma unroll 8
        for (int k = 0; k < 512; ++k) s += vm[k] * bf2f(wrow[k]);
        opad[(size_t)b2 * Ee + ccc] = s + bo[ccc];
        return;
    }

    const int cntb = cnt[b];
    if (qt * 128 >= cntb) return;

    const int tot = (cntb + 63) >> 6;
    const int hsplit = (tot + 1) >> 1;
    const int kstart = half ? hsplit : 0;
    const int kend = half ? tot : hsplit;

    // Q fragments (B-operand): lane = q-row (l31), k-chunk = hlf*8 within each 16-d group
    const int qrow = qt * 128 + wv * 32 + l31;
    const unsigned short* qp = qc + ((size_t)b * RPB + qrow) * HD + hd * Dd + hlf * 8;
    bf16x8 qf0 = *(const bf16x8*)(qp);
    bf16x8 qf1 = *(const bf16x8*)(qp + 16);
    bf16x8 qf2 = *(const bf16x8*)(qp + 32);
    bf16x8 qf3 = *(const bf16x8*)(qp + 48);

    const unsigned short* kcb = kc + (size_t)b * RPB * HD + hd * Dd;
    const unsigned short* vtb = vtc + ((size_t)b * HD + hd * Dd) * RPB;

    // Staging: linear LDS dest (glds requirement), inverse XOR-swizzle on SOURCE:
    // LDS chunk cp of row r holds logical chunk cp^(r&7)  -> b128 frag reads conflict-free.
    const int srow = tid >> 3, scp = tid & 7;
    auto STAGE = [&](int bufi, int kt_) {
        const int k0_ = kt_ * 64;
        const int sc = (scp ^ (srow & 7)) * 8;      // (srow+32)&7 == srow&7
        glds16(kcb + (size_t)(k0_ + srow) * HD + sc, &Ks[bufi][srow][scp * 8]);
        glds16(vtb + (size_t)srow * RPB + k0_ + sc, &Vs[bufi][srow][scp * 8]);
        glds16(kcb + (size_t)(k0_ + srow + 32) * HD + sc, &Ks[bufi][srow + 32][scp * 8]);
        glds16(vtb + (size_t)(srow + 32) * RPB + k0_ + sc, &Vs[bufi][srow + 32][scp * 8]);
    };

    float li = 0.f;
    f32x16 oa0 = {0,0,0,0,0,0,0,0,0,0,0,0,0,0,0,0};
    f32x16 oa1 = {0,0,0,0,0,0,0,0,0,0,0,0,0,0,0,0};
    const int rs = l31 & 7;

    int cur = 0;
    STAGE(0, kstart);
    for (int kt = kstart; kt < kend; ++kt) {
        asm volatile("" ::: "memory");
        __builtin_amdgcn_s_barrier();               // everyone done reading buf cur^1
        if (kt + 1 < kend) {
            STAGE(cur ^ 1, kt + 1);                 // 4 loads in flight across compute
            asm volatile("s_waitcnt vmcnt(4)" ::: "memory");
        } else {
            asm volatile("s_waitcnt vmcnt(0)" ::: "memory");
        }
        __builtin_amdgcn_s_barrier();               // buf cur visible everywhere
        asm volatile("" ::: "memory");

        const int k0 = kt * 64;

        // ---- QK^T swapped: sa = mfma(K, Q) -> C: col(l31)=q, rows(regs)=k ----
        f32x16 sa0 = {0,0,0,0,0,0,0,0,0,0,0,0,0,0,0,0};
        f32x16 sa1 = {0,0,0,0,0,0,0,0,0,0,0,0,0,0,0,0};
        __builtin_amdgcn_s_setprio(1);
        {
            bf16x8 kf;
            #define QKSTEP(dg, qf) \
                kf = *(const bf16x8*)&Ks[cur][l31][(((dg)*2 + hlf) ^ rs) * 8]; \
                sa0 = __builtin_amdgcn_mfma_f32_32x32x16_bf16(kf, qf, sa0, 0, 0, 0); \
                kf = *(const bf16x8*)&Ks[cur][32 + l31][(((dg)*2 + hlf) ^ rs) * 8]; \
                sa1 = __builtin_amdgcn_mfma_f32_32x32x16_bf16(kf, qf, sa1, 0, 0, 0);
            QKSTEP(0, qf0) QKSTEP(1, qf1) QKSTEP(2, qf2) QKSTEP(3, qf3)
            #undef QKSTEP
        }
        __builtin_amdgcn_s_setprio(0);

        // reg r -> k_local = (r&3) + 8*(r>>2) + 4*hlf  (sa1: +32)
        if (kt == tot - 1 && (cntb & 63)) {
            #pragma unroll
            for (int r = 0; r < 16; ++r) {
                int kl = k0 + (r & 3) + 8 * (r >> 2) + 4 * hlf;
                if (kl >= cntb) sa0[r] = -1e30f;
                if (kl + 32 >= cntb) sa1[r] = -1e30f;
            }
        }
        float p0[16], p1[16];
        #pragma unroll
        for (int r = 0; r < 16; ++r) { p0[r] = exp2f(sa0[r]); li += p0[r]; }
        #pragma unroll
        for (int r = 0; r < 16; ++r) { p1[r] = exp2f(sa1[r]); li += p1[r]; }

        // ---- P -> bf16 A-fragments, in-register (cvt_pk + permlane32_swap) ----
        union U8 { unsigned int u[4]; bf16x8 v8; };
        U8 pf0, pf1, pf2, pf3;
        {
            unsigned int w00 = cvtpk(p0[0],  p0[1]),  w01 = cvtpk(p0[2],  p0[3]);
            unsigned int w10 = cvtpk(p0[4],  p0[5]),  w11 = cvtpk(p0[6],  p0[7]);
            unsigned int w20 = cvtpk(p0[8],  p0[9]),  w21 = cvtpk(p0[10], p0[11]);
            unsigned int w30 = cvtpk(p0[12], p0[13]), w31 = cvtpk(p0[14], p0[15]);
            asm volatile("v_permlane32_swap_b32 %0, %1" : "+v"(w00), "+v"(w10));
            asm volatile("v_permlane32_swap_b32 %0, %1" : "+v"(w01), "+v"(w11));
            asm volatile("v_permlane32_swap_b32 %0, %1" : "+v"(w20), "+v"(w30));
            asm volatile("v_permlane32_swap_b32 %0, %1" : "+v"(w21), "+v"(w31));
            pf0.u[0] = w00; pf0.u[1] = w01; pf0.u[2] = w10; pf0.u[3] = w11;
            pf1.u[0] = w20; pf1.u[1] = w21; pf1.u[2] = w30; pf1.u[3] = w31;
        }
        {
            unsigned int w00 = cvtpk(p1[0],  p1[1]),  w01 = cvtpk(p1[2],  p1[3]);
            unsigned int w10 = cvtpk(p1[4],  p1[5]),  w11 = cvtpk(p1[6],  p1[7]);
            unsigned int w20 = cvtpk(p1[8],  p1[9]),  w21 = cvtpk(p1[10], p1[11]);
            unsigned int w30 = cvtpk(p1[12], p1[13]), w31 = cvtpk(p1[14], p1[15]);
            asm volatile("v_permlane32_swap_b32 %0, %1" : "+v"(w00), "+v"(w10));
            asm volatile("v_permlane32_swap_b32 %0, %1" : "+v"(w01), "+v"(w11));
            asm volatile("v_permlane32_swap_b32 %0, %1" : "+v"(w20), "+v"(w30));
            asm volatile("v_permlane32_swap_b32 %0, %1" : "+v"(w21), "+v"(w31));
            pf2.u[0] = w00; pf2.u[1] = w01; pf2.u[2] = w10; pf2.u[3] = w11;
            pf3.u[0] = w20; pf3.u[1] = w21; pf3.u[2] = w30; pf3.u[3] = w31;
        }

        // ---- PV: oacc = mfma(P, V^T) -> C: col(l31)=d, rows(regs)=q ----
        __builtin_amdgcn_s_setprio(1);
        {
            bf16x8 vf;
            #define PVSTEP(kcc, pf) \
                vf = *(const bf16x8*)&Vs[cur][l31][(((kcc)*2 + hlf) ^ rs) * 8]; \
                oa0 = __builtin_amdgcn_mfma_f32_32x32x16_bf16(pf.v8, vf, oa0, 0, 0, 0); \
                vf = *(const bf16x8*)&Vs[cur][32 + l31][(((kcc)*2 + hlf) ^ rs) * 8]; \
                oa1 = __builtin_amdgcn_mfma_f32_32x32x16_bf16(pf.v8, vf, oa1, 0, 0, 0);
            PVSTEP(0, pf0) PVSTEP(1, pf1) PVSTEP(2, pf2) PVSTEP(3, pf3)
            #undef PVSTEP
        }
        __builtin_amdgcn_s_setprio(0);

        cur ^= 1;
    }

    // lane pair (l, l^32) holds complementary halves of each q-row's sum
    li += __shfl_xor(li, 32);
    const size_t pbase = (((size_t)bh * QT2 + qt) * 2 + half) * (size_t)8192;
    const size_t lbase = (((size_t)bh * QT2 + qt) * 2 + half) * (size_t)128;
    if (hlf == 0) pL[lbase + wv * 32 + l31] = li;
    #pragma unroll
    for (int r = 0; r < 16; ++r) {
        int ql = (r & 3) + 8 * (r >> 2) + 4 * hlf;
        size_t rb = pbase + (size_t)(wv * 32 + ql) * 64;
        pO[rb + l31]      = f2bf(oa0[r]);
        pO[rb + 32 + l31] = f2bf(oa1[r]);
    }
}

// ---------------------------------------------------------------------------
// Kernel 4: gemm_out with FUSED combine of pO halves (128-row qt2 tiles).
// bx >= 768: fill padded out rows with out_pad[b].
// ---------------------------------------------------------------------------
__global__ __launch_bounds__(256) void gemm_out(
    const unsigned short* __restrict__ pO, const float* __restrict__ pL,
    const unsigned short* __restrict__ Wt, const float* __restrict__ bo,
    const int* __restrict__ idx, const int* __restrict__ cnt,
    const int* __restrict__ pad, const float* __restrict__ out_pad,
    float* __restrict__ out)
{
    const int bx = blockIdx.x;
    const int tid = threadIdx.x;

    if (bx >= Bb * 192) {
        const int fb = bx - Bb * 192;               // 0..31
        const int b = fb >> 3, seg = fb & 7;
        const int c0 = tid * 2;
        float2 op = *(const float2*)(out_pad + (size_t)b * Ee + c0);
        for (int r = 0; r < 256; ++r) {
            int s = seg * 256 + r;
            if (pad[b * Ss + s])
                *(float2*)(out + ((size_t)b * Ss + s) * Ee + c0) = op;
        }
        return;
    }

    const int b = bx / 192, t = bx - b * 192;
    const int at = t >> 3, bt = t & 7;
    const int cntb = cnt[b];
    if (at * 64 >= cntb) return;

    const int qt2 = at >> 1, sub = (at & 1) << 6;   // 128-row attn tile, 64-row half

    const unsigned short* Wz = Wt + (size_t)3 * 262144;
    const int lane = tid & 63, wv = tid >> 6;
    const int quad = lane >> 4, l15 = lane & 15;
    const int wm = (wv >> 1) * 32, wn = (wv & 1) * 32;
    const int sw = (l15 >> 1) & 3;
    const unsigned short* Bp = Wz + (size_t)bt * 64 * HD;

    __shared__ unsigned short As0[64][32], Bs0[64][32];
    __shared__ unsigned short As1[64][32], Bs1[64][32];
    __shared__ float invSh[512];   // [h][row]

    // precompute 1/lsum per (head, row)
    #pragma unroll
    for (int l = 0; l < 2; ++l) {
        int ix = tid + l * 256;
        int h = ix >> 6, row = ix & 63;
        size_t lb = (((size_t)(b * 8 + h) * QT2 + qt2) * 2) * 128 + sub;
        float lsum = pL[lb + row] + pL[lb + 128 + row];
        invSh[ix] = (lsum > 0.f) ? 1.0f / lsum : 0.f;
    }
    __syncthreads();

    f32x4 acc[2][2] = {};

    auto stageA = [&](unsigned short (&A)[64][32], int k0) {
        int r = tid >> 2, c = tid & 3;
        int swr = (r >> 1) & 3;
        int h = k0 >> 6;
        int d0 = (k0 & 63) + c * 8;
        const size_t pb = (((size_t)((b * 8 + h) * QT2 + qt2) * 2)) * 8192 + (size_t)(sub + r) * 64 + d0;
        union { uint4 q; unsigned short u[8]; } pa, pbh;
        pa.q  = *(const uint4*)(pO + pb);
        pbh.q = *(const uint4*)(pO + pb + 8192);
        float inv = invSh[h * 64 + r];
        uint4 o;
        o.x = cvtpk((bf2f(pa.u[0]) + bf2f(pbh.u[0])) * inv, (bf2f(pa.u[1]) + bf2f(pbh.u[1])) * inv);
        o.y = cvtpk((bf2f(pa.u[2]) + bf2f(pbh.u[2])) * inv, (bf2f(pa.u[3]) + bf2f(pbh.u[3])) * inv);
        o.z = cvtpk((bf2f(pa.u[4]) + bf2f(pbh.u[4])) * inv, (bf2f(pa.u[5]) + bf2f(pbh.u[5])) * inv);
        o.w = cvtpk((bf2f(pa.u[6]) + bf2f(pbh.u[6])) * inv, (bf2f(pa.u[7]) + bf2f(pbh.u[7])) * inv);
        *(uint4*)&A[r][(c ^ swr) * 8] = o;
    };
    auto stageB = [&](unsigned short (&B)[64][32], int k0) {
        int r = tid >> 2, c = tid & 3;
        int cg = (c ^ ((r >> 1) & 3)) * 8;
        glds16(Bp + (size_t)r * HD + k0 + cg, &B[r][c * 8]);
    };
    auto compute = [&](const unsigned short (&A)[64][32], const unsigned short (&B)[64][32]) {
        bf16x8 af[2], bfr[2];
        #pragma unroll
        for (int ms = 0; ms < 2; ++ms) af[ms] = *(const bf16x8*)&A[wm + ms * 16 + l15][(quad ^ sw) * 8];
        #pragma unroll
        for (int ns = 0; ns < 2; ++ns) bfr[ns] = *(const bf16x8*)&B[wn + ns * 16 + l15][(quad ^ sw) * 8];
        #pragma unroll
        for (int ms = 0; ms < 2; ++ms)
            #pragma unroll
            for (int ns = 0; ns < 2; ++ns)
                acc[ms][ns] = __builtin_amdgcn_mfma_f32_16x16x32_bf16(af[ms], bfr[ns], acc[ms][ns], 0, 0, 0);
    };

    stageA(As0, 0); stageB(Bs0, 0);
    for (int ki = 0; ki < 16; ki += 2) {
        __syncthreads();
        if (ki + 1 < 16) { stageA(As1, (ki + 1) * 32); stageB(Bs1, (ki + 1) * 32); }
        compute(As0, Bs0);
        __syncthreads();
        if (ki + 2 < 16) { stageA(As0, (ki + 2) * 32); stageB(Bs0, (ki + 2) * 32); }
        compute(As1, Bs1);
    }

    #pragma unroll
    for (int ns = 0; ns < 2; ++ns) {
        int col = bt * 64 + wn + ns * 16 + l15;
        float bb = bo[col];
        #pragma unroll
        for (int ms = 0; ms < 2; ++ms) {
            #pragma unroll
            for (int r = 0; r < 4; ++r) {
                int m = at * 64 + wm + ms * 16 + quad * 4 + r;
                if (m < cntb) {
                    int srow = idx[b * Ss + m];
                    out[((size_t)b * Ss + srow) * Ee + col] = acc[ms][ns][r] + bb;
                }
            }
        }
    }
}

extern "C" void kernel_launch(void* const* d_in, const int* in_sizes, int n_in,
                              void* d_out, int out_size, void* d_ws, size_t ws_size,
                              hipStream_t stream) {
    const float* x   = (const float*)d_in[0];
    const int*   pad = (const int*)  d_in[1];
    const float* Wq  = (const float*)d_in[2];
    const float* bq  = (const float*)d_in[3];
    const float* Wk  = (const float*)d_in[4];
    const float* bk  = (const float*)d_in[5];
    const float* Wv  = (const float*)d_in[6];
    const float* bv  = (const float*)d_in[7];
    const float* Wo  = (const float*)d_in[8];
    const float* bo  = (const float*)d_in[9];
    float* out = (float*)d_out;

    const size_t csz = (size_t)Bb * RPB * HD;            // 3,145,728 elems
    unsigned short* Wt  = (unsigned short*)d_ws;         // 1,048,576 shorts
    unsigned short* qc  = Wt + 1048576;
    unsigned short* kc  = qc + csz;
    unsigned short* vtc = kc + csz;
    unsigned short* xc  = vtc + csz;                     // [4][1536][512]
    unsigned short* pO  = xc;                            // alias: xc dead after gemm_qkvt
    unsigned short* tail = xc + 6291456;                 // pO = 32*12*2*8192
    float* xpart = (float*)tail;                         // 64*512 fp32
    int*   idxw  = (int*)(xpart + 64 * 512);             // 8192
    int*   cntw  = idxw + Mm;                            // 4
    float* vmw   = (float*)(cntw + 4);                   // 4*512
    float* opad  = vmw + Bb * HD;                        // 4*512
    float* pLw   = opad + Bb * Ee;                       // 32*12*2*128 fp32

    prep2<<<320, 256, 0, stream>>>(x, pad, Wq, Wk, Wv, Wo, Wt, xc, xpart, idxw, cntw);

    dim3 g1(Bb * 192, 1, 3);
    gemm_qkvt<<<g1, 256, 0, stream>>>(xc, Wt, bq, bk, bv, cntw, xpart, qc, kc, vtc, vmw);

    dim3 g2(Bb * Hh, QT2 + 1, 2);
    attn<<<g2, 256, 0, stream>>>(qc, kc, vtc, cntw, pO, pLw, vmw, Wt, bo, opad);

    dim3 g3(Bb * 192 + 32, 1);
    gemm_out<<<g3, 256, 0, stream>>>(pO, pLw, Wt, bo, idxw, cntw, pad, opad, out);
}

// Round 2
// 159.992 us; speedup vs baseline: 1.0194x; 1.0194x over previous
//
#include <hip/hip_runtime.h>
#include <hip/hip_bf16.h>
#include <math.h>

#define Bb 4
#define Ss 2048
#define Ee 512
#define Hh 8
#define Dd 64
#define HD 512
#define Mm (Bb*Ss)
#define RPB 1536      // compacted rows-per-batch capacity (cnt ~1024)
#define QT2 12        // 128-row q-tiles per batch (RPB/128)

using bf16x8 = __attribute__((ext_vector_type(8))) short;
using f32x4  = __attribute__((ext_vector_type(4))) float;
using f32x16 = __attribute__((ext_vector_type(16))) float;

typedef __attribute__((address_space(1))) const unsigned int gu32;
typedef __attribute__((address_space(3))) unsigned int lu32;
__device__ inline void glds16(const void* g, void* l) {
    __builtin_amdgcn_global_load_lds((gu32*)g, (lu32*)l, 16, 0, 0);
}

__device__ inline unsigned short f2bf(float f) {
    unsigned int u = __float_as_uint(f);
    unsigned int r = (u + 0x7fffu + ((u >> 16) & 1u)) >> 16;
    return (unsigned short)r;
}
__device__ inline float bf2f(unsigned short u) {
    return __uint_as_float((unsigned int)u << 16);
}
__device__ inline unsigned int cvtpk(float a, float b) {
    float2 t; t.x = a; t.y = b;
    union { __hip_bfloat162 h; unsigned int u; } z;
    z.h = __float22bfloat162_rn(t);
    return z.u;
}

// ---------------------------------------------------------------------------
// Kernel 1: prep2 = wconv (256 blocks) + scan+gather+xpart (128 blocks of
// 64 rows each -> 2x the CU coverage of the x read vs 64 blocks).
// ---------------------------------------------------------------------------
__global__ __launch_bounds__(256) void prep2(
    const float* __restrict__ x, const int* __restrict__ pad,
    const float* __restrict__ Wq, const float* __restrict__ Wk,
    const float* __restrict__ Wv, const float* __restrict__ Wo,
    unsigned short* __restrict__ Wt, unsigned short* __restrict__ xc,
    float* __restrict__ xpart, int* __restrict__ idx, int* __restrict__ cnt)
{
    __shared__ union ShMem {
        float T[64][68];
        struct { int sc[256]; int rk[64]; float sm[4][512]; } g;
    } sh;
    const int bi = blockIdx.x, tid = threadIdx.x;

    if (bi < 256) {
        const int w = bi >> 6;
        const float* W = (w == 0) ? Wq : (w == 1) ? Wk : (w == 2) ? Wv : Wo;
        const int tk0 = ((bi >> 3) & 7) * 64, tn0 = (bi & 7) * 64;
        #pragma unroll
        for (int l = 0; l < 4; ++l) {
            int fi = tid + l * 256;
            int r = fi >> 4, c4 = (fi & 15) * 4;
            *(float4*)&sh.T[r][c4] = *(const float4*)(W + (size_t)(tk0 + r) * Ee + tn0 + c4);
        }
        __syncthreads();
        #pragma unroll
        for (int l = 0; l < 4; ++l) {
            int fi = tid + l * 256;
            int r2 = fi >> 4, c4 = (fi & 15) * 4;
            uint2 o;
            o.x = cvtpk(sh.T[c4 + 0][r2], sh.T[c4 + 1][r2]);
            o.y = cvtpk(sh.T[c4 + 2][r2], sh.T[c4 + 3][r2]);
            *(uint2*)(Wt + (size_t)w * 262144 + (size_t)(tn0 + r2) * Ee + tk0 + c4) = o;
        }
        return;
    }

    // ---- gather blocks: gb = (b, chunk i of 64 rows), i in 0..31 ----
    const int gb = bi - 256;
    const int b = gb >> 5, i = gb & 31;

    int loc[8], c = 0;
    #pragma unroll
    for (int j = 0; j < 8; ++j) {
        loc[j] = pad[b * Ss + tid * 8 + j];
        c += (loc[j] == 0);
    }
    sh.g.sc[tid] = c;
    __syncthreads();
    for (int s = 1; s < 256; s <<= 1) {
        int v = (tid >= s) ? sh.g.sc[tid - s] : 0;
        __syncthreads();
        sh.g.sc[tid] += v;
        __syncthreads();
    }
    // stripe owners within our 64-row chunk (8 threads x 8 rows)
    if (tid >= i * 8 && tid < i * 8 + 8) {
        int off = sh.g.sc[tid] - c;
        int lbase = (tid - i * 8) * 8;
        #pragma unroll
        for (int j = 0; j < 8; ++j) {
            if (loc[j] == 0) {
                idx[b * Ss + off] = tid * 8 + j;
                sh.g.rk[lbase + j] = off;
                ++off;
            } else sh.g.rk[lbase + j] = -1;
        }
    }
    if (i == 31 && tid == 255) cnt[b] = sh.g.sc[255];
    __syncthreads();

    const int c8 = (tid & 63) * 8, grp = tid >> 6;
    float a8[8] = {};
    for (int it = 0; it < 16; ++it) {
        int lr = grp * 16 + it;
        int s = i * 64 + lr;
        const float* pr = x + ((size_t)b * Ss + s) * Ee + c8;
        float4 f0 = *(const float4*)pr;
        float4 f1 = *(const float4*)(pr + 4);
        a8[0] += f0.x; a8[1] += f0.y; a8[2] += f0.z; a8[3] += f0.w;
        a8[4] += f1.x; a8[5] += f1.y; a8[6] += f1.z; a8[7] += f1.w;
        int rkk = sh.g.rk[lr];
        if (rkk >= 0) {
            uint4 v;
            v.x = cvtpk(f0.x, f0.y); v.y = cvtpk(f0.z, f0.w);
            v.z = cvtpk(f1.x, f1.y); v.w = cvtpk(f1.z, f1.w);
            *(uint4*)(xc + ((size_t)b * RPB + rkk) * Ee + c8) = v;
        }
    }
    #pragma unroll
    for (int j = 0; j < 8; ++j) sh.g.sm[grp][c8 + j] = a8[j];
    __syncthreads();
    int c0 = tid * 2;
    float s0 = sh.g.sm[0][c0] + sh.g.sm[1][c0] + sh.g.sm[2][c0] + sh.g.sm[3][c0];
    float s1 = sh.g.sm[0][c0 + 1] + sh.g.sm[1][c0 + 1] + sh.g.sm[2][c0 + 1] + sh.g.sm[3][c0 + 1];
    float2 o; o.x = s0; o.y = s1;
    *(float2*)(xpart + (size_t)(b * 32 + i) * Ee + c0) = o;
}

// ---------------------------------------------------------------------------
// Kernel 2: gemm_qkvt, 128x128 tiles (m97 structure), XOR-swizzled LDS.
// Grid (4b*48, 1, 3).  z==2 && bt==11 (4 blocks): vmean = xmean@Wv + bv.
// ---------------------------------------------------------------------------
__global__ __launch_bounds__(256) void gemm_qkvt(
    const unsigned short* __restrict__ xc, const unsigned short* __restrict__ Wt,
    const float* __restrict__ bq, const float* __restrict__ bk, const float* __restrict__ bv,
    const int* __restrict__ cnt, const float* __restrict__ xpart,
    unsigned short* __restrict__ qo, unsigned short* __restrict__ ko,
    unsigned short* __restrict__ vt, float* __restrict__ vmw)
{
    const int z = blockIdx.z;
    const int bx = blockIdx.x;
    const int b = bx / 48, t = bx - b * 48;
    const int at = (z < 2) ? (t >> 2) : (t & 3);
    const int bt = (z < 2) ? (t & 3) : (t >> 2);
    const int cntb = cnt[b];
    const int tid = threadIdx.x, lane = tid & 63, wv = tid >> 6;
    const int quad = lane >> 4, l15 = lane & 15;
    const int wm = (wv >> 1) * 64, wn = (wv & 1) * 64;
    const int sw = (l15 >> 1) & 3;

    __shared__ unsigned short As0[128][32], Bs0[128][32];
    __shared__ unsigned short As1[128][32], Bs1[128][32];

    if (z == 2 && bt == 11) {
        // vmean: 4 blocks (at=0..3), 128 cols each
        float* xm = (float*)&As0[0][0];
        for (int kk = tid; kk < 512; kk += 256) {
            float s = 0.f;
            #pragma unroll
            for (int p = 0; p < 32; ++p) s += xpart[(size_t)(b * 32 + p) * Ee + kk];
            xm[kk] = s;
        }
        __syncthreads();
        int col = at * 128 + (tid >> 1);
        int kh = (tid & 1) * 256;
        const unsigned short* wrow = Wt + (size_t)2 * 262144 + (size_t)col * Ee + kh;
        float s = 0.f;
        #pragma unroll 8
        for (int kk = 0; kk < 256; ++kk) s += xm[kh + kk] * bf2f(wrow[kk]);
        s += __shfl_xor(s, 1);
        if ((tid & 1) == 0) vmw[(size_t)b * HD + col] = s * (1.0f / 2048.0f) + bv[col];
        return;
    }

    const int xcTile = (z < 2) ? at : bt;
    if (xcTile * 128 >= cntb) return;

    const unsigned short *Ap, *Bp;
    if (z < 2) {
        Ap = xc + ((size_t)b * RPB + at * 128) * Ee;
        Bp = Wt + (size_t)z * 262144 + (size_t)bt * 128 * Ee;
    } else {
        Ap = Wt + (size_t)2 * 262144 + (size_t)at * 128 * Ee;
        Bp = xc + ((size_t)b * RPB + bt * 128) * Ee;
    }

    f32x4 acc[4][4] = {};

    auto stage = [&](unsigned short (&A)[128][32], unsigned short (&B)[128][32], int k0) {
        #pragma unroll
        for (int l = 0; l < 2; ++l) {
            int id = tid + l * 256;
            int r = id >> 2, c = id & 3;
            int cg = (c ^ ((r >> 1) & 3)) * 8;
            glds16(Ap + (size_t)r * Ee + k0 + cg, &A[r][c * 8]);
            glds16(Bp + (size_t)r * Ee + k0 + cg, &B[r][c * 8]);
        }
    };
    auto compute = [&](const unsigned short (&A)[128][32], const unsigned short (&B)[128][32]) {
        bf16x8 af[4], bfr[4];
        #pragma unroll
        for (int ms = 0; ms < 4; ++ms) af[ms] = *(const bf16x8*)&A[wm + ms * 16 + l15][(quad ^ sw) * 8];
        #pragma unroll
        for (int ns = 0; ns < 4; ++ns) bfr[ns] = *(const bf16x8*)&B[wn + ns * 16 + l15][(quad ^ sw) * 8];
        #pragma unroll
        for (int ms = 0; ms < 4; ++ms)
            #pragma unroll
            for (int ns = 0; ns < 4; ++ns)
                acc[ms][ns] = __builtin_amdgcn_mfma_f32_16x16x32_bf16(af[ms], bfr[ns], acc[ms][ns], 0, 0, 0);
    };

    stage(As0, Bs0, 0);
    for (int ki = 0; ki < 16; ki += 2) {
        __syncthreads();
        if (ki + 1 < 16) stage(As1, Bs1, (ki + 1) * 32);
        compute(As0, Bs0);
        __syncthreads();
        if (ki + 2 < 16) stage(As0, Bs0, (ki + 2) * 32);
        compute(As1, Bs1);
    }

    if (z < 2) {
        const float* bias = z ? bk : bq;
        unsigned short* dst = z ? ko : qo;
        #pragma unroll
        for (int ns = 0; ns < 4; ++ns) {
            int col = bt * 128 + wn + ns * 16 + l15;
            float bb = bias[col];
            #pragma unroll
            for (int ms = 0; ms < 4; ++ms) {
                #pragma unroll
                for (int r = 0; r < 4; ++r) {
                    int m = at * 128 + wm + ms * 16 + quad * 4 + r;
                    float val = acc[ms][ns][r] + bb;
                    if (z == 0) val *= 0.18033688f;   // 0.125 * log2(e)
                    dst[((size_t)b * RPB + m) * HD + col] = f2bf(val);
                }
            }
        }
    } else {
        #pragma unroll
        for (int ms = 0; ms < 4; ++ms) {
            #pragma unroll
            for (int r = 0; r < 4; ++r) {
                int dg = at * 128 + wm + ms * 16 + quad * 4 + r;
                float bb = bv[dg];
                #pragma unroll
                for (int ns = 0; ns < 4; ++ns) {
                    int col = bt * 128 + wn + ns * 16 + l15;
                    vt[((size_t)b * HD + dg) * RPB + col] = f2bf(acc[ms][ns][r] + bb);
                }
            }
        }
    }
}

// ---------------------------------------------------------------------------
// Kernel 3: attention, QBLK=128 (4 waves x 32q), 32x32x16 MFMA, swapped QK^T,
// in-register P via cvt_pk + v_permlane32_swap, double-buffered K/V staging
// with counted vmcnt.  Grid (32 bh, QT2+1, 2).  k-split=2.
// ---------------------------------------------------------------------------
__global__ __launch_bounds__(256, 2) void attn(
    const unsigned short* __restrict__ qc, const unsigned short* __restrict__ kc,
    const unsigned short* __restrict__ vtc, const int* __restrict__ cnt,
    unsigned short* __restrict__ pO, float* __restrict__ pL,
    const float* __restrict__ vmw, const unsigned short* __restrict__ Wt,
    const float* __restrict__ bo, float* __restrict__ opad)
{
    __shared__ unsigned short Ks[2][64][64], Vs[2][64][64];

    const int tid = threadIdx.x, wv = tid >> 6, lane = tid & 63;
    const int l31 = lane & 31, hlf = lane >> 5;
    const int bh = blockIdx.x, b = bh >> 3, hd = bh & 7;
    const int qt = blockIdx.y, half = blockIdx.z;

    if (qt >= QT2) {
        if (half || bh >= 8) return;
        const int b2 = bh >> 1, seg = bh & 1;
        float* vm = (float*)&Ks[0][0][0];
        for (int t = tid; t < 512; t += 256) vm[t] = vmw[(size_t)b2 * HD + t];
        __syncthreads();
        int ccc = seg * 256 + tid;
        const unsigned short* wrow = Wt + (size_t)3 * 262144 + (size_t)ccc * HD;
        float s = 0.f;
        #pragma unroll 8
        for (int k = 0; k < 512; ++k) s += vm[k] * bf2f(wrow[k]);
        opad[(size_t)b2 * Ee + ccc] = s + bo[ccc];
        return;
    }

    const int cntb = cnt[b];
    if (qt * 128 >= cntb) return;

    const int tot = (cntb + 63) >> 6;
    const int hsplit = (tot + 1) >> 1;
    const int kstart = half ? hsplit : 0;
    const int kend = half ? tot : hsplit;

    const int qrow = qt * 128 + wv * 32 + l31;
    const unsigned short* qp = qc + ((size_t)b * RPB + qrow) * HD + hd * Dd + hlf * 8;
    bf16x8 qf0 = *(const bf16x8*)(qp);
    bf16x8 qf1 = *(const bf16x8*)(qp + 16);
    bf16x8 qf2 = *(const bf16x8*)(qp + 32);
    bf16x8 qf3 = *(const bf16x8*)(qp + 48);

    const unsigned short* kcb = kc + (size_t)b * RPB * HD + hd * Dd;
    const unsigned short* vtb = vtc + ((size_t)b * HD + hd * Dd) * RPB;

    const int srow = tid >> 3, scp = tid & 7;
    auto STAGE = [&](int bufi, int kt_) {
        const int k0_ = kt_ * 64;
        const int sc = (scp ^ (srow & 7)) * 8;
        glds16(kcb + (size_t)(k0_ + srow) * HD + sc, &Ks[bufi][srow][scp * 8]);
        glds16(vtb + (size_t)srow * RPB + k0_ + sc, &Vs[bufi][srow][scp * 8]);
        glds16(kcb + (size_t)(k0_ + srow + 32) * HD + sc, &Ks[bufi][srow + 32][scp * 8]);
        glds16(vtb + (size_t)(srow + 32) * RPB + k0_ + sc, &Vs[bufi][srow + 32][scp * 8]);
    };

    float li = 0.f;
    f32x16 oa0 = {0,0,0,0,0,0,0,0,0,0,0,0,0,0,0,0};
    f32x16 oa1 = {0,0,0,0,0,0,0,0,0,0,0,0,0,0,0,0};
    const int rs = l31 & 7;

    int cur = 0;
    STAGE(0, kstart);
    for (int kt = kstart; kt < kend; ++kt) {
        asm volatile("" ::: "memory");
        __builtin_amdgcn_s_barrier();
        if (kt + 1 < kend) {
            STAGE(cur ^ 1, kt + 1);
            asm volatile("s_waitcnt vmcnt(4)" ::: "memory");
        } else {
            asm volatile("s_waitcnt vmcnt(0)" ::: "memory");
        }
        __builtin_amdgcn_s_barrier();
        asm volatile("" ::: "memory");

        const int k0 = kt * 64;

        f32x16 sa0 = {0,0,0,0,0,0,0,0,0,0,0,0,0,0,0,0};
        f32x16 sa1 = {0,0,0,0,0,0,0,0,0,0,0,0,0,0,0,0};
        __builtin_amdgcn_s_setprio(1);
        {
            bf16x8 kf;
            #define QKSTEP(dg, qf) \
                kf = *(const bf16x8*)&Ks[cur][l31][(((dg)*2 + hlf) ^ rs) * 8]; \
                sa0 = __builtin_amdgcn_mfma_f32_32x32x16_bf16(kf, qf, sa0, 0, 0, 0); \
                kf = *(const bf16x8*)&Ks[cur][32 + l31][(((dg)*2 + hlf) ^ rs) * 8]; \
                sa1 = __builtin_amdgcn_mfma_f32_32x32x16_bf16(kf, qf, sa1, 0, 0, 0);
            QKSTEP(0, qf0) QKSTEP(1, qf1) QKSTEP(2, qf2) QKSTEP(3, qf3)
            #undef QKSTEP
        }
        __builtin_amdgcn_s_setprio(0);

        if (kt == tot - 1 && (cntb & 63)) {
            #pragma unroll
            for (int r = 0; r < 16; ++r) {
                int kl = k0 + (r & 3) + 8 * (r >> 2) + 4 * hlf;
                if (kl >= cntb) sa0[r] = -1e30f;
                if (kl + 32 >= cntb) sa1[r] = -1e30f;
            }
        }
        float p0[16], p1[16];
        #pragma unroll
        for (int r = 0; r < 16; ++r) { p0[r] = exp2f(sa0[r]); li += p0[r]; }
        #pragma unroll
        for (int r = 0; r < 16; ++r) { p1[r] = exp2f(sa1[r]); li += p1[r]; }

        union U8 { unsigned int u[4]; bf16x8 v8; };
        U8 pf0, pf1, pf2, pf3;
        {
            unsigned int w00 = cvtpk(p0[0],  p0[1]),  w01 = cvtpk(p0[2],  p0[3]);
            unsigned int w10 = cvtpk(p0[4],  p0[5]),  w11 = cvtpk(p0[6],  p0[7]);
            unsigned int w20 = cvtpk(p0[8],  p0[9]),  w21 = cvtpk(p0[10], p0[11]);
            unsigned int w30 = cvtpk(p0[12], p0[13]), w31 = cvtpk(p0[14], p0[15]);
            asm volatile("v_permlane32_swap_b32 %0, %1" : "+v"(w00), "+v"(w10));
            asm volatile("v_permlane32_swap_b32 %0, %1" : "+v"(w01), "+v"(w11));
            asm volatile("v_permlane32_swap_b32 %0, %1" : "+v"(w20), "+v"(w30));
            asm volatile("v_permlane32_swap_b32 %0, %1" : "+v"(w21), "+v"(w31));
            pf0.u[0] = w00; pf0.u[1] = w01; pf0.u[2] = w10; pf0.u[3] = w11;
            pf1.u[0] = w20; pf1.u[1] = w21; pf1.u[2] = w30; pf1.u[3] = w31;
        }
        {
            unsigned int w00 = cvtpk(p1[0],  p1[1]),  w01 = cvtpk(p1[2],  p1[3]);
            unsigned int w10 = cvtpk(p1[4],  p1[5]),  w11 = cvtpk(p1[6],  p1[7]);
            unsigned int w20 = cvtpk(p1[8],  p1[9]),  w21 = cvtpk(p1[10], p1[11]);
            unsigned int w30 = cvtpk(p1[12], p1[13]), w31 = cvtpk(p1[14], p1[15]);
            asm volatile("v_permlane32_swap_b32 %0, %1" : "+v"(w00), "+v"(w10));
            asm volatile("v_permlane32_swap_b32 %0, %1" : "+v"(w01), "+v"(w11));
            asm volatile("v_permlane32_swap_b32 %0, %1" : "+v"(w20), "+v"(w30));
            asm volatile("v_permlane32_swap_b32 %0, %1" : "+v"(w21), "+v"(w31));
            pf2.u[0] = w00; pf2.u[1] = w01; pf2.u[2] = w10; pf2.u[3] = w11;
            pf3.u[0] = w20; pf3.u[1] = w21; pf3.u[2] = w30; pf3.u[3] = w31;
        }

        __builtin_amdgcn_s_setprio(1);
        {
            bf16x8 vf;
            #define PVSTEP(kcc, pf) \
                vf = *(const bf16x8*)&Vs[cur][l31][(((kcc)*2 + hlf) ^ rs) * 8]; \
                oa0 = __builtin_amdgcn_mfma_f32_32x32x16_bf16(pf.v8, vf, oa0, 0, 0, 0); \
                vf = *(const bf16x8*)&Vs[cur][32 + l31][(((kcc)*2 + hlf) ^ rs) * 8]; \
                oa1 = __builtin_amdgcn_mfma_f32_32x32x16_bf16(pf.v8, vf, oa1, 0, 0, 0);
            PVSTEP(0, pf0) PVSTEP(1, pf1) PVSTEP(2, pf2) PVSTEP(3, pf3)
            #undef PVSTEP
        }
        __builtin_amdgcn_s_setprio(0);

        cur ^= 1;
    }

    li += __shfl_xor(li, 32);
    const size_t pbase = (((size_t)bh * QT2 + qt) * 2 + half) * (size_t)8192;
    const size_t lbase = (((size_t)bh * QT2 + qt) * 2 + half) * (size_t)128;
    if (hlf == 0) pL[lbase + wv * 32 + l31] = li;
    #pragma unroll
    for (int r = 0; r < 16; ++r) {
        int ql = (r & 3) + 8 * (r >> 2) + 4 * hlf;
        size_t rb = pbase + (size_t)(wv * 32 + ql) * 64;
        pO[rb + l31]      = f2bf(oa0[r]);
        pO[rb + 32 + l31] = f2bf(oa1[r]);
    }
}

// ---------------------------------------------------------------------------
// Kernel 4: gemm_out, 128x128 tiles, FUSED combine of pO halves.
// Tile at == attn q-tile qt.  Grid (4b*48 + 32).
// ---------------------------------------------------------------------------
__global__ __launch_bounds__(256) void gemm_out(
    const unsigned short* __restrict__ pO, const float* __restrict__ pL,
    const unsigned short* __restrict__ Wt, const float* __restrict__ bo,
    const int* __restrict__ idx, const int* __restrict__ cnt,
    const int* __restrict__ pad, const float* __restrict__ out_pad,
    float* __restrict__ out)
{
    const int bx = blockIdx.x;
    const int tid = threadIdx.x;

    if (bx >= Bb * 48) {
        const int fb = bx - Bb * 48;                // 0..31
        const int b = fb >> 3, seg = fb & 7;
        const int c0 = tid * 2;
        float2 op = *(const float2*)(out_pad + (size_t)b * Ee + c0);
        for (int r = 0; r < 256; ++r) {
            int s = seg * 256 + r;
            if (pad[b * Ss + s])
                *(float2*)(out + ((size_t)b * Ss + s) * Ee + c0) = op;
        }
        return;
    }

    const int b = bx / 48, t = bx - b * 48;
    const int at = t >> 2, bt = t & 3;              // at: 128-row attn tile (==qt)
    const int cntb = cnt[b];
    if (at * 128 >= cntb) return;

    const unsigned short* Wz = Wt + (size_t)3 * 262144;
    const int lane = tid & 63, wv = tid >> 6;
    const int quad = lane >> 4, l15 = lane & 15;
    const int wm = (wv >> 1) * 64, wn = (wv & 1) * 64;
    const int sw = (l15 >> 1) & 3;
    const unsigned short* Bp = Wz + (size_t)bt * 128 * HD;

    __shared__ unsigned short As0[128][32], Bs0[128][32];
    __shared__ unsigned short As1[128][32], Bs1[128][32];
    __shared__ float invSh[1024];   // [h][row 0..127]

    #pragma unroll
    for (int l = 0; l < 4; ++l) {
        int ix = tid + l * 256;
        int h = ix >> 7, row = ix & 127;
        size_t lb = (((size_t)(b * 8 + h) * QT2 + at) * 2) * 128;
        float lsum = pL[lb + row] + pL[lb + 128 + row];
        invSh[ix] = (lsum > 0.f) ? 1.0f / lsum : 0.f;
    }
    __syncthreads();

    f32x4 acc[4][4] = {};

    auto stageA = [&](unsigned short (&A)[128][32], int k0) {
        #pragma unroll
        for (int l = 0; l < 2; ++l) {
            int id = tid + l * 256;
            int r = id >> 2, c = id & 3;
            int swr = (r >> 1) & 3;
            int h = k0 >> 6;
            int d0 = (k0 & 63) + c * 8;
            const size_t pb = (((size_t)((b * 8 + h) * QT2 + at) * 2)) * 8192 + (size_t)r * 64 + d0;
            union { uint4 q; unsigned short u[8]; } pa, pbh;
            pa.q  = *(const uint4*)(pO + pb);
            pbh.q = *(const uint4*)(pO + pb + 8192);
            float inv = invSh[h * 128 + r];
            uint4 o;
            o.x = cvtpk((bf2f(pa.u[0]) + bf2f(pbh.u[0])) * inv, (bf2f(pa.u[1]) + bf2f(pbh.u[1])) * inv);
            o.y = cvtpk((bf2f(pa.u[2]) + bf2f(pbh.u[2])) * inv, (bf2f(pa.u[3]) + bf2f(pbh.u[3])) * inv);
            o.z = cvtpk((bf2f(pa.u[4]) + bf2f(pbh.u[4])) * inv, (bf2f(pa.u[5]) + bf2f(pbh.u[5])) * inv);
            o.w = cvtpk((bf2f(pa.u[6]) + bf2f(pbh.u[6])) * inv, (bf2f(pa.u[7]) + bf2f(pbh.u[7])) * inv);
            *(uint4*)&A[r][(c ^ swr) * 8] = o;
        }
    };
    auto stageB = [&](unsigned short (&B)[128][32], int k0) {
        #pragma unroll
        for (int l = 0; l < 2; ++l) {
            int id = tid + l * 256;
            int r = id >> 2, c = id & 3;
            int cg = (c ^ ((r >> 1) & 3)) * 8;
            glds16(Bp + (size_t)r * HD + k0 + cg, &B[r][c * 8]);
        }
    };
    auto compute = [&](const unsigned short (&A)[128][32], const unsigned short (&B)[128][32]) {
        bf16x8 af[4], bfr[4];
        #pragma unroll
        for (int ms = 0; ms < 4; ++ms) af[ms] = *(const bf16x8*)&A[wm + ms * 16 + l15][(quad ^ sw) * 8];
        #pragma unroll
        for (int ns = 0; ns < 4; ++ns) bfr[ns] = *(const bf16x8*)&B[wn + ns * 16 + l15][(quad ^ sw) * 8];
        #pragma unroll
        for (int ms = 0; ms < 4; ++ms)
            #pragma unroll
            for (int ns = 0; ns < 4; ++ns)
                acc[ms][ns] = __builtin_amdgcn_mfma_f32_16x16x32_bf16(af[ms], bfr[ns], acc[ms][ns], 0, 0, 0);
    };

    stageA(As0, 0); stageB(Bs0, 0);
    for (int ki = 0; ki < 16; ki += 2) {
        __syncthreads();
        if (ki + 1 < 16) { stageA(As1, (ki + 1) * 32); stageB(Bs1, (ki + 1) * 32); }
        compute(As0, Bs0);
        __syncthreads();
        if (ki + 2 < 16) { stageA(As0, (ki + 2) * 32); stageB(Bs0, (ki + 2) * 32); }
        compute(As1, Bs1);
    }

    #pragma unroll
    for (int ns = 0; ns < 4; ++ns) {
        int col = bt * 128 + wn + ns * 16 + l15;
        float bb = bo[col];
        #pragma unroll
        for (int ms = 0; ms < 4; ++ms) {
            #pragma unroll
            for (int r = 0; r < 4; ++r) {
                int m = at * 128 + wm + ms * 16 + quad * 4 + r;
                if (m < cntb) {
                    int srow = idx[b * Ss + m];
                    out[((size_t)b * Ss + srow) * Ee + col] = acc[ms][ns][r] + bb;
                }
            }
        }
    }
}

extern "C" void kernel_launch(void* const* d_in, const int* in_sizes, int n_in,
                              void* d_out, int out_size, void* d_ws, size_t ws_size,
                              hipStream_t stream) {
    const float* x   = (const float*)d_in[0];
    const int*   pad = (const int*)  d_in[1];
    const float* Wq  = (const float*)d_in[2];
    const float* bq  = (const float*)d_in[3];
    const float* Wk  = (const float*)d_in[4];
    const float* bk  = (const float*)d_in[5];
    const float* Wv  = (const float*)d_in[6];
    const float* bv  = (const float*)d_in[7];
    const float* Wo  = (const float*)d_in[8];
    const float* bo  = (const float*)d_in[9];
    float* out = (float*)d_out;

    const size_t csz = (size_t)Bb * RPB * HD;            // 3,145,728 elems
    unsigned short* Wt  = (unsigned short*)d_ws;         // 1,048,576 shorts
    unsigned short* qc  = Wt + 1048576;
    unsigned short* kc  = qc + csz;
    unsigned short* vtc = kc + csz;
    unsigned short* xc  = vtc + csz;                     // [4][1536][512]
    unsigned short* pO  = xc;                            // alias: xc dead after gemm_qkvt
    unsigned short* tail = xc + 6291456;                 // pO = 32*12*2*8192
    float* xpart = (float*)tail;                         // 128*512 fp32
    int*   idxw  = (int*)(xpart + 128 * 512);            // 8192
    int*   cntw  = idxw + Mm;                            // 4
    float* vmw   = (float*)(cntw + 4);                   // 4*512
    float* opad  = vmw + Bb * HD;                        // 4*512
    float* pLw   = opad + Bb * Ee;                       // 32*12*2*128 fp32

    prep2<<<384, 256, 0, stream>>>(x, pad, Wq, Wk, Wv, Wo, Wt, xc, xpart, idxw, cntw);

    dim3 g1(Bb * 48, 1, 3);
    gemm_qkvt<<<g1, 256, 0, stream>>>(xc, Wt, bq, bk, bv, cntw, xpart, qc, kc, vtc, vmw);

    dim3 g2(Bb * Hh, QT2 + 1, 2);
    attn<<<g2, 256, 0, stream>>>(qc, kc, vtc, cntw, pO, pLw, vmw, Wt, bo, opad);

    dim3 g3(Bb * 48 + 32, 1);
    gemm_out<<<g3, 256, 0, stream>>>(pO, pLw, Wt, bo, idxw, cntw, pad, opad, out);
}